// Round 3
// baseline (1230.320 us; speedup 1.0000x reference)
//
#include <hip/hip_runtime.h>

#define S_ 1024
#define D_ 512
#define DCH 16      // denom chunk length
#define NDCH 64     // chunks per batch

// ---------------------------------------------------------------------------
// GEMM + bias + activation.  C[m,n] = act(sum_k A[m,k]*B[k,n] + bias[n])
// MODE 0: proj   A=x   (lda 512),  B=W_in (ldb 2048), N=1536, tanh for n<1024
// MODE 1: gates  A=v   (lda 1536), B=W_ig/W_fg/W_og (ldb 512), sigmoid;
//                g==0 (i-gate) fused to i*k (k read from qkv).
// MODE 2: out    A=hs  (lda 512),  B=W_out (ldb 512), N=512, no act
// ---------------------------------------------------------------------------
template<int MODE>
__global__ __launch_bounds__(256)
void gemm_act(const float* __restrict__ A, int lda,
              const float* __restrict__ W0, const float* __restrict__ W1,
              const float* __restrict__ W2,
              const float* __restrict__ bb0, const float* __restrict__ bb1,
              const float* __restrict__ bb2,
              float* __restrict__ Co, int ldc)
{
    const int tid = threadIdx.x;
    const int n0  = blockIdx.x * 128;
    const int m0  = blockIdx.y * 128;

    const float* Bp; const float* bias; int ldb;
    if (MODE == 1) {
        const int g  = n0 >> 9;
        const int nn = n0 & 511;
        Bp   = (g == 0 ? W0 : g == 1 ? W1 : W2) + nn;
        bias = (g == 0 ? bb0 : g == 1 ? bb1 : bb2) + nn;
        ldb  = 512;
    } else {
        Bp   = W0 + n0;
        bias = bb0 + n0;
        ldb  = (MODE == 0 ? 2048 : 512);
    }

    __shared__ float As[16][128];   // K-major
    __shared__ float Bs[16][128];

    float acc[8][8];
#pragma unroll
    for (int i = 0; i < 8; ++i)
#pragma unroll
        for (int j = 0; j < 8; ++j) acc[i][j] = 0.f;

    const int ar = tid >> 2;
    const int ac = (tid & 3) * 4;
    const int br = tid >> 5;
    const int bc = (tid & 31) * 4;
    const int ty = tid >> 4;
    const int tx = tid & 15;

    const float* Ap = A + (size_t)(m0 + ar) * lda + ac;
    const float* Bq = Bp + (size_t)br * ldb + bc;

    for (int k0 = 0; k0 < 512; k0 += 16) {
        float4 a0 = *(const float4*)(Ap);
        float4 a1 = *(const float4*)(Ap + (size_t)64 * lda);
        float4 b0 = *(const float4*)(Bq);
        float4 b1 = *(const float4*)(Bq + (size_t)8 * ldb);
        Ap += 16; Bq += (size_t)16 * ldb;

        __syncthreads();
        As[ac + 0][ar]      = a0.x; As[ac + 1][ar]      = a0.y;
        As[ac + 2][ar]      = a0.z; As[ac + 3][ar]      = a0.w;
        As[ac + 0][ar + 64] = a1.x; As[ac + 1][ar + 64] = a1.y;
        As[ac + 2][ar + 64] = a1.z; As[ac + 3][ar + 64] = a1.w;
        *(float4*)&Bs[br][bc]     = b0;
        *(float4*)&Bs[br + 8][bc] = b1;
        __syncthreads();

#pragma unroll
        for (int kk = 0; kk < 16; ++kk) {
            float4 aL = *(const float4*)&As[kk][ty * 4];
            float4 aH = *(const float4*)&As[kk][64 + ty * 4];
            float4 bL = *(const float4*)&Bs[kk][tx * 4];
            float4 bH = *(const float4*)&Bs[kk][64 + tx * 4];
            float av[8] = {aL.x, aL.y, aL.z, aL.w, aH.x, aH.y, aH.z, aH.w};
            float bv[8] = {bL.x, bL.y, bL.z, bL.w, bH.x, bH.y, bH.z, bH.w};
#pragma unroll
            for (int i = 0; i < 8; ++i)
#pragma unroll
                for (int j = 0; j < 8; ++j)
                    acc[i][j] = fmaf(av[i], bv[j], acc[i][j]);
        }
    }

    float bv[8];
#pragma unroll
    for (int j = 0; j < 8; ++j) {
        const int c = (j < 4) ? (tx * 4 + j) : (64 + tx * 4 + j - 4);
        bv[j] = bias[c];
    }
#pragma unroll
    for (int i = 0; i < 8; ++i) {
        const int m = m0 + ((i < 4) ? (ty * 4 + i) : (64 + ty * 4 + i - 4));
        float vals[8];
#pragma unroll
        for (int j = 0; j < 8; ++j) {
            float v = acc[i][j] + bv[j];
            if (MODE == 0) {
                const int cg = n0 + ((j < 4) ? (tx * 4 + j) : (64 + tx * 4 + j - 4));
                if (cg < 1024) v = tanhf(v);
            } else if (MODE == 1) {
                v = 1.0f / (1.0f + expf(-v));
            }
            vals[j] = v;
        }
        if (MODE == 1 && n0 < 512) {
            const float* krow = A + (size_t)m * lda - 512;
            float4 kl = *(const float4*)(krow + n0 + tx * 4);
            float4 kh = *(const float4*)(krow + n0 + 64 + tx * 4);
            vals[0] *= kl.x; vals[1] *= kl.y; vals[2] *= kl.z; vals[3] *= kl.w;
            vals[4] *= kh.x; vals[5] *= kh.y; vals[6] *= kh.z; vals[7] *= kh.w;
        }
        float* row = Co + (size_t)m * ldc + n0;
        *(float4*)&row[tx * 4]      = make_float4(vals[0], vals[1], vals[2], vals[3]);
        *(float4*)&row[64 + tx * 4] = make_float4(vals[4], vals[5], vals[6], vals[7]);
    }
}

// ---------------------------------------------------------------------------
// n-scan pipeline (f64):  local chunk-16 scans -> stitch -> per-chunk denom
// replay with one WAVE per chunk (no barriers) and T=4 batched fold-reduce.
// ---------------------------------------------------------------------------
__global__ __launch_bounds__(512)
void nscan_local(const float* __restrict__ GG,
                 double* __restrict__ nend, double* __restrict__ Dend)
{
    const int b = blockIdx.x >> 6;
    const int c = blockIdx.x & 63;
    const int d = threadIdx.x;
    const float* gb = GG + (size_t)b * S_ * 1536 + (size_t)c * DCH * 1536;
    double n = 0.0, P = 1.0;
    for (int u = 0; u < DCH; ++u) {
        const float* row = gb + (size_t)u * 1536;
        const double ik = (double)row[d];
        const double f  = (double)row[512 + d];
        n = fma(f, n, ik);
        P *= f;
    }
    nend[(size_t)blockIdx.x * 512 + d] = n;
    Dend[(size_t)blockIdx.x * 512 + d] = P;
}

__global__ __launch_bounds__(512)
void nscan_stitch(const double* __restrict__ nend, const double* __restrict__ Dend,
                  double* __restrict__ n0a, float* __restrict__ nfO)
{
    const int b = blockIdx.x;
    const int d = threadIdx.x;
    double n0 = 0.0;
    for (int c = 0; c < NDCH; ++c) {
        const size_t idx = ((size_t)(b * NDCH + c)) * 512 + d;
        n0a[idx] = n0;
        n0 = fma(Dend[idx], n0, nend[idx]);
    }
    nfO[(size_t)b * 512 + d] = (float)n0;
}

// one wave per chunk of 16 steps; lane owns d = 4*lane + j + 256*r
__global__ __launch_bounds__(256)
void denom_kernel(const float* __restrict__ QKV, const float* __restrict__ GG,
                  const double* __restrict__ n0a, float* __restrict__ invd)
{
    const int lane = threadIdx.x & 63;
    const int widx = blockIdx.x * 4 + (threadIdx.x >> 6);
    const int b    = widx >> 6;
    const int c    = widx & 63;
    const int d0   = 4 * lane;

    const float* qb = QKV + (size_t)b * S_ * 1536 + (size_t)c * DCH * 1536;
    const float* gb = GG  + (size_t)b * S_ * 1536 + (size_t)c * DCH * 1536;
    const double* sp = n0a + (size_t)widx * 512;

    double n[2][4];
#pragma unroll
    for (int r = 0; r < 2; ++r) {
        double2 a = *(const double2*)(sp + d0 + 256 * r);
        double2 bb = *(const double2*)(sp + d0 + 256 * r + 2);
        n[r][0] = a.x; n[r][1] = a.y; n[r][2] = bb.x; n[r][3] = bb.y;
    }

    for (int t0 = 0; t0 < DCH; t0 += 4) {
        double dq[4];
#pragma unroll
        for (int i = 0; i < 4; ++i) {
            const float* qr = qb + (size_t)(t0 + i) * 1536;
            const float* gr = gb + (size_t)(t0 + i) * 1536;
            double acc = 0.0;
#pragma unroll
            for (int r = 0; r < 2; ++r) {
                float4 qf = *(const float4*)(qr + d0 + 256 * r);
                float4 kf = *(const float4*)(gr + d0 + 256 * r);
                float4 ff = *(const float4*)(gr + 512 + d0 + 256 * r);
                const float* qp = (const float*)&qf;
                const float* kp = (const float*)&kf;
                const float* fp = (const float*)&ff;
#pragma unroll
                for (int j = 0; j < 4; ++j) {
                    n[r][j] = fma((double)fp[j], n[r][j], (double)kp[j]);
                    acc = fma((double)qp[j], n[r][j], acc);
                }
            }
            dq[i] = acc;
        }
        // batched fold-reduce of 4 doubles over 64 lanes
        double u0 = dq[0] + __shfl_xor(dq[0], 32);
        double u1 = dq[1] + __shfl_xor(dq[1], 32);
        double u2 = dq[2] + __shfl_xor(dq[2], 32);
        double u3 = dq[3] + __shfl_xor(dq[3], 32);
        double w0 = (lane & 32) ? u2 : u0;
        double w1 = (lane & 32) ? u3 : u1;
        w0 += __shfl_xor(w0, 16);
        w1 += __shfl_xor(w1, 16);
        double y = (lane & 16) ? w1 : w0;
        y += __shfl_xor(y, 8); y += __shfl_xor(y, 4);
        y += __shfl_xor(y, 2); y += __shfl_xor(y, 1);
        if ((lane & 15) == 0) {
            const int g = lane >> 4;
            const double den = (y > 1e-6) ? y : 1e-6;
            invd[(size_t)b * S_ + c * DCH + t0 + g] = (float)(1.0 / den);
        }
    }
}

// ---------------------------------------------------------------------------
// Recurrent scan.  grid = 1024 blocks x 256 thr = 4096 waves (4/SIMD).
// b = bid&7 (XCD-local batch); wave owns ONE e-column, all 512 d
// (d = 4*lane + j + 256*r).  T=4 time-unroll with batched fold-reduce:
// 6 shuffle-latencies per 4 steps instead of 24.
// ---------------------------------------------------------------------------
__global__ __launch_bounds__(256)
void scan_kernel(const float* __restrict__ QKV, const float* __restrict__ GG,
                 const float* __restrict__ invd,
                 float* __restrict__ hs, float* __restrict__ CfO,
                 float* __restrict__ hlO)
{
    const int tid  = threadIdx.x;
    const int lane = tid & 63;
    const int w    = tid >> 6;
    const int bid  = blockIdx.x;
    const int b    = bid & 7;
    const int e    = (bid >> 3) * 4 + w;      // 0..511
    const int d0   = 4 * lane;

    const float* qb  = QKV + (size_t)b * S_ * 1536;
    const float* gb  = GG  + (size_t)b * S_ * 1536;
    const float* ivb = invd + (size_t)b * S_;

    float C[2][4];
#pragma unroll
    for (int r = 0; r < 2; ++r)
#pragma unroll
        for (int j = 0; j < 4; ++j) C[r][j] = 0.f;

    for (int t0 = 0; t0 < S_; t0 += 4) {
        float4 q[4][2], f[4][2], ik[4][2];
        float v[4], o[4], iv[4];
#pragma unroll
        for (int i = 0; i < 4; ++i) {
            const float* r1 = qb + (size_t)(t0 + i) * 1536;
            const float* r2 = gb + (size_t)(t0 + i) * 1536;
            q[i][0]  = *(const float4*)(r1 + d0);
            q[i][1]  = *(const float4*)(r1 + 256 + d0);
            ik[i][0] = *(const float4*)(r2 + d0);
            ik[i][1] = *(const float4*)(r2 + 256 + d0);
            f[i][0]  = *(const float4*)(r2 + 512 + d0);
            f[i][1]  = *(const float4*)(r2 + 768 + d0);
            v[i]  = r1[1024 + e];
            o[i]  = r2[1024 + e];
            iv[i] = ivb[t0 + i];
        }

        float p[4];
#pragma unroll
        for (int i = 0; i < 4; ++i) {
            float acc = 0.f;
#pragma unroll
            for (int r = 0; r < 2; ++r) {
                const float* qp = (const float*)&q[i][r];
                const float* kp = (const float*)&ik[i][r];
                const float* fp = (const float*)&f[i][r];
#pragma unroll
                for (int j = 0; j < 4; ++j) {
                    C[r][j] = fmaf(fp[j], C[r][j], kp[j] * v[i]);
                    acc = fmaf(qp[j], C[r][j], acc);
                }
            }
            p[i] = acc;
        }

        // batched fold-reduce: 4 sums over 64 lanes, chain = 6 shuffles
        float u0 = p[0] + __shfl_xor(p[0], 32);
        float u1 = p[1] + __shfl_xor(p[1], 32);
        float u2 = p[2] + __shfl_xor(p[2], 32);
        float u3 = p[3] + __shfl_xor(p[3], 32);
        float w0 = (lane & 32) ? u2 : u0;
        float w1 = (lane & 32) ? u3 : u1;
        w0 += __shfl_xor(w0, 16);
        w1 += __shfl_xor(w1, 16);
        float y = (lane & 16) ? w1 : w0;
        y += __shfl_xor(y, 8); y += __shfl_xor(y, 4);
        y += __shfl_xor(y, 2); y += __shfl_xor(y, 1);

        if ((lane & 15) == 0) {
            const int g = lane >> 4;          // which step of the window
            const float h = o[g] * y * iv[g];
            hs[((size_t)(b * S_ + t0 + g)) * 512 + e] = h;
            if (t0 + g == S_ - 1) hlO[(size_t)b * 512 + e] = h;
        }
    }

    // final C (scatter stores; 8 MB total once)
#pragma unroll
    for (int r = 0; r < 2; ++r)
#pragma unroll
        for (int j = 0; j < 4; ++j) {
            const int d = d0 + j + 256 * r;
            CfO[((size_t)b * 512 + d) * 512 + e] = C[r][j];
        }
}

// ---------------------------------------------------------------------------
extern "C" void kernel_launch(void* const* d_in, const int* in_sizes, int n_in,
                              void* d_out, int out_size, void* d_ws, size_t ws_size,
                              hipStream_t stream)
{
    const float* x    = (const float*)d_in[0];
    const float* W_in = (const float*)d_in[1];
    const float* b_in = (const float*)d_in[2];
    const float* W_ig = (const float*)d_in[3];
    const float* b_ig = (const float*)d_in[4];
    const float* W_fg = (const float*)d_in[5];
    const float* b_fg = (const float*)d_in[6];
    const float* W_og = (const float*)d_in[7];
    const float* b_og = (const float*)d_in[8];
    const float* W_out= (const float*)d_in[9];
    const float* b_out= (const float*)d_in[10];

    float* out   = (float*)d_out;                       // [8,1024,512]
    float* CfO   = out + (size_t)8 * 1024 * 512;        // [8,512,512]
    float* nfO   = CfO + (size_t)8 * 512 * 512;         // [8,512]
    float* hlO   = nfO + (size_t)8 * 512;               // [8,512]

    float* qkv = (float*)d_ws;                          // [8192,1536] q|k|v
    float* gg  = qkv + (size_t)8192 * 1536;             // [8192,1536] ik|f|o
    float* hsb = gg  + (size_t)8192 * 1536;             // [8192,512]
    // transient n-scan scratch overlaid on hsb (dead before scan_kernel writes)
    double* nend = (double*)hsb;                        // [512][512] f64 (2MB)
    double* Dend = nend + (size_t)8 * NDCH * 512;
    double* n0a  = Dend + (size_t)8 * NDCH * 512;
    float*  invd = hsb + (size_t)8192 * 512;            // [8,1024]

    // 1. proj + tanh(q,k)
    gemm_act<0><<<dim3(12, 64), 256, 0, stream>>>(
        x, 512, W_in, W_in, W_in, b_in, b_in, b_in, qkv, 1536);
    // 2. gates: [i*k | f | o]
    gemm_act<1><<<dim3(12, 64), 256, 0, stream>>>(
        qkv + 1024, 1536, W_ig, W_fg, W_og, b_ig, b_fg, b_og, gg, 1536);
    // 3. n-scan + denominators (f64)
    nscan_local <<<512, 512, 0, stream>>>(gg, nend, Dend);
    nscan_stitch<<<  8, 512, 0, stream>>>(nend, Dend, n0a, nfO);
    denom_kernel<<<128, 256, 0, stream>>>(qkv, gg, n0a, invd);
    // 4. recurrent scan (C only)
    scan_kernel<<<1024, 256, 0, stream>>>(qkv, gg, invd, hsb, CfO, hlO);
    // 5. out = hs @ W_out + b_out
    gemm_act<2><<<dim3(4, 64), 256, 0, stream>>>(
        hsb, 512, W_out, W_out, W_out, b_out, b_out, b_out, out, 512);
}

// Round 4
// 1229.990 us; speedup vs baseline: 1.0003x; 1.0003x over previous
//
#include <hip/hip_runtime.h>

#define S_ 1024
#define D_ 512
#define DCH 16      // denom chunk length
#define NDCH 64     // chunks per batch

// ---------------------------------------------------------------------------
// GEMM + bias + activation.  C[m,n] = act(sum_k A[m,k]*B[k,n] + bias[n])
// MODE 0: proj   A=x   (lda 512),  B=W_in (ldb 2048), N=1536, tanh for n<1024
// MODE 1: gates  A=v   (lda 1536), B=W_ig/W_fg/W_og (ldb 512), sigmoid;
//                g==0 (i-gate) fused to i*k (k read from qkv).
// MODE 2: out    A=hs  (lda 512),  B=W_out (ldb 512), N=512, no act
// ---------------------------------------------------------------------------
template<int MODE>
__global__ __launch_bounds__(256)
void gemm_act(const float* __restrict__ A, int lda,
              const float* __restrict__ W0, const float* __restrict__ W1,
              const float* __restrict__ W2,
              const float* __restrict__ bb0, const float* __restrict__ bb1,
              const float* __restrict__ bb2,
              float* __restrict__ Co, int ldc)
{
    const int tid = threadIdx.x;
    const int n0  = blockIdx.x * 128;
    const int m0  = blockIdx.y * 128;

    const float* Bp; const float* bias; int ldb;
    if (MODE == 1) {
        const int g  = n0 >> 9;
        const int nn = n0 & 511;
        Bp   = (g == 0 ? W0 : g == 1 ? W1 : W2) + nn;
        bias = (g == 0 ? bb0 : g == 1 ? bb1 : bb2) + nn;
        ldb  = 512;
    } else {
        Bp   = W0 + n0;
        bias = bb0 + n0;
        ldb  = (MODE == 0 ? 2048 : 512);
    }

    __shared__ float As[16][128];   // K-major
    __shared__ float Bs[16][128];

    float acc[8][8];
#pragma unroll
    for (int i = 0; i < 8; ++i)
#pragma unroll
        for (int j = 0; j < 8; ++j) acc[i][j] = 0.f;

    const int ar = tid >> 2;
    const int ac = (tid & 3) * 4;
    const int br = tid >> 5;
    const int bc = (tid & 31) * 4;
    const int ty = tid >> 4;
    const int tx = tid & 15;

    const float* Ap = A + (size_t)(m0 + ar) * lda + ac;
    const float* Bq = Bp + (size_t)br * ldb + bc;

    for (int k0 = 0; k0 < 512; k0 += 16) {
        float4 a0 = *(const float4*)(Ap);
        float4 a1 = *(const float4*)(Ap + (size_t)64 * lda);
        float4 b0 = *(const float4*)(Bq);
        float4 b1 = *(const float4*)(Bq + (size_t)8 * ldb);
        Ap += 16; Bq += (size_t)16 * ldb;

        __syncthreads();
        As[ac + 0][ar]      = a0.x; As[ac + 1][ar]      = a0.y;
        As[ac + 2][ar]      = a0.z; As[ac + 3][ar]      = a0.w;
        As[ac + 0][ar + 64] = a1.x; As[ac + 1][ar + 64] = a1.y;
        As[ac + 2][ar + 64] = a1.z; As[ac + 3][ar + 64] = a1.w;
        *(float4*)&Bs[br][bc]     = b0;
        *(float4*)&Bs[br + 8][bc] = b1;
        __syncthreads();

#pragma unroll
        for (int kk = 0; kk < 16; ++kk) {
            float4 aL = *(const float4*)&As[kk][ty * 4];
            float4 aH = *(const float4*)&As[kk][64 + ty * 4];
            float4 bL = *(const float4*)&Bs[kk][tx * 4];
            float4 bH = *(const float4*)&Bs[kk][64 + tx * 4];
            float av[8] = {aL.x, aL.y, aL.z, aL.w, aH.x, aH.y, aH.z, aH.w};
            float bv[8] = {bL.x, bL.y, bL.z, bL.w, bH.x, bH.y, bH.z, bH.w};
#pragma unroll
            for (int i = 0; i < 8; ++i)
#pragma unroll
                for (int j = 0; j < 8; ++j)
                    acc[i][j] = fmaf(av[i], bv[j], acc[i][j]);
        }
    }

    float bv[8];
#pragma unroll
    for (int j = 0; j < 8; ++j) {
        const int c = (j < 4) ? (tx * 4 + j) : (64 + tx * 4 + j - 4);
        bv[j] = bias[c];
    }
#pragma unroll
    for (int i = 0; i < 8; ++i) {
        const int m = m0 + ((i < 4) ? (ty * 4 + i) : (64 + ty * 4 + i - 4));
        float vals[8];
#pragma unroll
        for (int j = 0; j < 8; ++j) {
            float v = acc[i][j] + bv[j];
            if (MODE == 0) {
                const int cg = n0 + ((j < 4) ? (tx * 4 + j) : (64 + tx * 4 + j - 4));
                if (cg < 1024) v = tanhf(v);
            } else if (MODE == 1) {
                v = 1.0f / (1.0f + expf(-v));
            }
            vals[j] = v;
        }
        if (MODE == 1 && n0 < 512) {
            const float* krow = A + (size_t)m * lda - 512;
            float4 kl = *(const float4*)(krow + n0 + tx * 4);
            float4 kh = *(const float4*)(krow + n0 + 64 + tx * 4);
            vals[0] *= kl.x; vals[1] *= kl.y; vals[2] *= kl.z; vals[3] *= kl.w;
            vals[4] *= kh.x; vals[5] *= kh.y; vals[6] *= kh.z; vals[7] *= kh.w;
        }
        float* row = Co + (size_t)m * ldc + n0;
        *(float4*)&row[tx * 4]      = make_float4(vals[0], vals[1], vals[2], vals[3]);
        *(float4*)&row[64 + tx * 4] = make_float4(vals[4], vals[5], vals[6], vals[7]);
    }
}

// ---------------------------------------------------------------------------
// n-scan pipeline (f64):  local chunk-16 scans -> stitch -> per-chunk denom
// replay with one WAVE per chunk (no barriers) and T=4 batched fold-reduce.
// ---------------------------------------------------------------------------
__global__ __launch_bounds__(512)
void nscan_local(const float* __restrict__ GG,
                 double* __restrict__ nend, double* __restrict__ Dend)
{
    const int b = blockIdx.x >> 6;
    const int c = blockIdx.x & 63;
    const int d = threadIdx.x;
    const float* gb = GG + (size_t)b * S_ * 1536 + (size_t)c * DCH * 1536;
    double n = 0.0, P = 1.0;
    for (int u = 0; u < DCH; ++u) {
        const float* row = gb + (size_t)u * 1536;
        const double ik = (double)row[d];
        const double f  = (double)row[512 + d];
        n = fma(f, n, ik);
        P *= f;
    }
    nend[(size_t)blockIdx.x * 512 + d] = n;
    Dend[(size_t)blockIdx.x * 512 + d] = P;
}

__global__ __launch_bounds__(512)
void nscan_stitch(const double* __restrict__ nend, const double* __restrict__ Dend,
                  double* __restrict__ n0a, float* __restrict__ nfO)
{
    const int b = blockIdx.x;
    const int d = threadIdx.x;
    double n0 = 0.0;
    for (int c = 0; c < NDCH; ++c) {
        const size_t idx = ((size_t)(b * NDCH + c)) * 512 + d;
        n0a[idx] = n0;
        n0 = fma(Dend[idx], n0, nend[idx]);
    }
    nfO[(size_t)b * 512 + d] = (float)n0;
}

// one wave per chunk of 16 steps; lane owns d = 4*lane + j + 256*r
__global__ __launch_bounds__(256)
void denom_kernel(const float* __restrict__ QKV, const float* __restrict__ GG,
                  const double* __restrict__ n0a, float* __restrict__ invd)
{
    const int lane = threadIdx.x & 63;
    const int widx = blockIdx.x * 4 + (threadIdx.x >> 6);
    const int b    = widx >> 6;
    const int c    = widx & 63;
    const int d0   = 4 * lane;

    const float* qb = QKV + (size_t)b * S_ * 1536 + (size_t)c * DCH * 1536;
    const float* gb = GG  + (size_t)b * S_ * 1536 + (size_t)c * DCH * 1536;
    const double* sp = n0a + (size_t)widx * 512;

    double n[2][4];
#pragma unroll
    for (int r = 0; r < 2; ++r) {
        double2 a = *(const double2*)(sp + d0 + 256 * r);
        double2 bb = *(const double2*)(sp + d0 + 256 * r + 2);
        n[r][0] = a.x; n[r][1] = a.y; n[r][2] = bb.x; n[r][3] = bb.y;
    }

    for (int t0 = 0; t0 < DCH; t0 += 4) {
        double dq[4];
#pragma unroll
        for (int i = 0; i < 4; ++i) {
            const float* qr = qb + (size_t)(t0 + i) * 1536;
            const float* gr = gb + (size_t)(t0 + i) * 1536;
            double acc = 0.0;
#pragma unroll
            for (int r = 0; r < 2; ++r) {
                float4 qf = *(const float4*)(qr + d0 + 256 * r);
                float4 kf = *(const float4*)(gr + d0 + 256 * r);
                float4 ff = *(const float4*)(gr + 512 + d0 + 256 * r);
                const float* qp = (const float*)&qf;
                const float* kp = (const float*)&kf;
                const float* fp = (const float*)&ff;
#pragma unroll
                for (int j = 0; j < 4; ++j) {
                    n[r][j] = fma((double)fp[j], n[r][j], (double)kp[j]);
                    acc = fma((double)qp[j], n[r][j], acc);
                }
            }
            dq[i] = acc;
        }
        // batched fold-reduce of 4 doubles over 64 lanes
        double u0 = dq[0] + __shfl_xor(dq[0], 32);
        double u1 = dq[1] + __shfl_xor(dq[1], 32);
        double u2 = dq[2] + __shfl_xor(dq[2], 32);
        double u3 = dq[3] + __shfl_xor(dq[3], 32);
        double w0 = (lane & 32) ? u2 : u0;
        double w1 = (lane & 32) ? u3 : u1;
        w0 += __shfl_xor(w0, 16);
        w1 += __shfl_xor(w1, 16);
        double y = (lane & 16) ? w1 : w0;
        y += __shfl_xor(y, 8); y += __shfl_xor(y, 4);
        y += __shfl_xor(y, 2); y += __shfl_xor(y, 1);
        if ((lane & 15) == 0) {
            const int g = lane >> 4;
            const double den = (y > 1e-6) ? y : 1e-6;
            invd[(size_t)b * S_ + c * DCH + t0 + g] = (float)(1.0 / den);
        }
    }
}

// ---------------------------------------------------------------------------
// Recurrent scan.  grid = 1024 blocks x 256 thr = 4096 waves (4/SIMD).
// b = bid&7 (XCD-local batch); wave owns ONE e-column, all 512 d
// (d = 4*lane + j + 256*r).  T=4 time-unroll with batched fold-reduce:
// 6 shuffle-latencies per 4 steps instead of 24.
// ---------------------------------------------------------------------------
__global__ __launch_bounds__(256)
void scan_kernel(const float* __restrict__ QKV, const float* __restrict__ GG,
                 const float* __restrict__ invd,
                 float* __restrict__ hs, float* __restrict__ CfO,
                 float* __restrict__ hlO)
{
    const int tid  = threadIdx.x;
    const int lane = tid & 63;
    const int w    = tid >> 6;
    const int bid  = blockIdx.x;
    const int b    = bid & 7;
    const int e    = (bid >> 3) * 4 + w;      // 0..511
    const int d0   = 4 * lane;

    const float* qb  = QKV + (size_t)b * S_ * 1536;
    const float* gb  = GG  + (size_t)b * S_ * 1536;
    const float* ivb = invd + (size_t)b * S_;

    float C[2][4];
#pragma unroll
    for (int r = 0; r < 2; ++r)
#pragma unroll
        for (int j = 0; j < 4; ++j) C[r][j] = 0.f;

    for (int t0 = 0; t0 < S_; t0 += 4) {
        float4 q[4][2], f[4][2], ik[4][2];
        float v[4], o[4], iv[4];
#pragma unroll
        for (int i = 0; i < 4; ++i) {
            const float* r1 = qb + (size_t)(t0 + i) * 1536;
            const float* r2 = gb + (size_t)(t0 + i) * 1536;
            q[i][0]  = *(const float4*)(r1 + d0);
            q[i][1]  = *(const float4*)(r1 + 256 + d0);
            ik[i][0] = *(const float4*)(r2 + d0);
            ik[i][1] = *(const float4*)(r2 + 256 + d0);
            f[i][0]  = *(const float4*)(r2 + 512 + d0);
            f[i][1]  = *(const float4*)(r2 + 768 + d0);
            v[i]  = r1[1024 + e];
            o[i]  = r2[1024 + e];
            iv[i] = ivb[t0 + i];
        }

        float p[4];
#pragma unroll
        for (int i = 0; i < 4; ++i) {
            float acc = 0.f;
#pragma unroll
            for (int r = 0; r < 2; ++r) {
                const float* qp = (const float*)&q[i][r];
                const float* kp = (const float*)&ik[i][r];
                const float* fp = (const float*)&f[i][r];
#pragma unroll
                for (int j = 0; j < 4; ++j) {
                    C[r][j] = fmaf(fp[j], C[r][j], kp[j] * v[i]);
                    acc = fmaf(qp[j], C[r][j], acc);
                }
            }
            p[i] = acc;
        }

        // batched fold-reduce: 4 sums over 64 lanes, chain = 6 shuffles
        float u0 = p[0] + __shfl_xor(p[0], 32);
        float u1 = p[1] + __shfl_xor(p[1], 32);
        float u2 = p[2] + __shfl_xor(p[2], 32);
        float u3 = p[3] + __shfl_xor(p[3], 32);
        float w0 = (lane & 32) ? u2 : u0;
        float w1 = (lane & 32) ? u3 : u1;
        w0 += __shfl_xor(w0, 16);
        w1 += __shfl_xor(w1, 16);
        float y = (lane & 16) ? w1 : w0;
        y += __shfl_xor(y, 8); y += __shfl_xor(y, 4);
        y += __shfl_xor(y, 2); y += __shfl_xor(y, 1);

        if ((lane & 15) == 0) {
            const int g = lane >> 4;          // which step of the window
            const float h = o[g] * y * iv[g];
            hs[((size_t)(b * S_ + t0 + g)) * 512 + e] = h;
            if (t0 + g == S_ - 1) hlO[(size_t)b * 512 + e] = h;
        }
    }

    // final C (scatter stores; 8 MB total once)
#pragma unroll
    for (int r = 0; r < 2; ++r)
#pragma unroll
        for (int j = 0; j < 4; ++j) {
            const int d = d0 + j + 256 * r;
            CfO[((size_t)b * 512 + d) * 512 + e] = C[r][j];
        }
}

// ---------------------------------------------------------------------------
extern "C" void kernel_launch(void* const* d_in, const int* in_sizes, int n_in,
                              void* d_out, int out_size, void* d_ws, size_t ws_size,
                              hipStream_t stream)
{
    const float* x    = (const float*)d_in[0];
    const float* W_in = (const float*)d_in[1];
    const float* b_in = (const float*)d_in[2];
    const float* W_ig = (const float*)d_in[3];
    const float* b_ig = (const float*)d_in[4];
    const float* W_fg = (const float*)d_in[5];
    const float* b_fg = (const float*)d_in[6];
    const float* W_og = (const float*)d_in[7];
    const float* b_og = (const float*)d_in[8];
    const float* W_out= (const float*)d_in[9];
    const float* b_out= (const float*)d_in[10];

    float* out   = (float*)d_out;                       // [8,1024,512]
    float* CfO   = out + (size_t)8 * 1024 * 512;        // [8,512,512]
    float* nfO   = CfO + (size_t)8 * 512 * 512;         // [8,512]
    float* hlO   = nfO + (size_t)8 * 512;               // [8,512]

    float* qkv = (float*)d_ws;                          // [8192,1536] q|k|v
    float* gg  = qkv + (size_t)8192 * 1536;             // [8192,1536] ik|f|o
    float* hsb = gg  + (size_t)8192 * 1536;             // [8192,512]
    // transient n-scan scratch overlaid on hsb (dead before scan_kernel writes)
    double* nend = (double*)hsb;                        // [512][512] f64 (2MB)
    double* Dend = nend + (size_t)8 * NDCH * 512;
    double* n0a  = Dend + (size_t)8 * NDCH * 512;
    float*  invd = hsb + (size_t)8192 * 512;            // [8,1024]

    // 1. proj + tanh(q,k)
    gemm_act<0><<<dim3(12, 64), 256, 0, stream>>>(
        x, 512, W_in, W_in, W_in, b_in, b_in, b_in, qkv, 1536);
    // 2. gates: [i*k | f | o]
    gemm_act<1><<<dim3(12, 64), 256, 0, stream>>>(
        qkv + 1024, 1536, W_ig, W_fg, W_og, b_ig, b_fg, b_og, gg, 1536);
    // 3. n-scan + denominators (f64)
    nscan_local <<<512, 512, 0, stream>>>(gg, nend, Dend);
    nscan_stitch<<<  8, 512, 0, stream>>>(nend, Dend, n0a, nfO);
    denom_kernel<<<128, 256, 0, stream>>>(qkv, gg, n0a, invd);
    // 4. recurrent scan (C only)
    scan_kernel<<<1024, 256, 0, stream>>>(qkv, gg, invd, hsb, CfO, hlO);
    // 5. out = hs @ W_out + b_out
    gemm_act<2><<<dim3(4, 64), 256, 0, stream>>>(
        hsb, 512, W_out, W_out, W_out, b_out, b_out, b_out, out, 512);
}